// Round 5
// baseline (2187.434 us; speedup 1.0000x reference)
//
#include <hip/hip_runtime.h>
#include <stdint.h>

#define BATCH 512
#define SEQ   256
#define EMBD  64
#define HID   128
#define GATES 512
#define NST   18
#define LROW  (BATCH * NST)   /* 9216 floats per time slice */

typedef short  bf16x8 __attribute__((ext_vector_type(8)));
typedef float  f32x4  __attribute__((ext_vector_type(4)));

__device__ __forceinline__ short f2bf(float f) {
  unsigned u = __float_as_uint(f);
  u = (u + 0x7FFFu + ((u >> 16) & 1u)) >> 16;
  return (short)u;
}
__device__ __forceinline__ float rcpf(float x) { return __builtin_amdgcn_rcpf(x); }

// lgkm-only barrier (vmem ops stay in flight across it).
__device__ __forceinline__ void lds_barrier() {
  __builtin_amdgcn_sched_barrier(0);
  asm volatile("s_waitcnt lgkmcnt(0)");
  __builtin_amdgcn_s_barrier();
  __builtin_amdgcn_sched_barrier(0);
}

// ---------------- K1: embedding gather, time-major bf16 ----------------
__global__ void k_embed(const int* __restrict__ inputs, const float* __restrict__ E,
                        short* __restrict__ emb) {
  int tid = blockIdx.x * 256 + threadIdx.x;   // 2^21 threads total
  int e4 = (tid & 15) << 2;
  int b  = (tid >> 4) & (BATCH - 1);
  int t  = tid >> 13;
  int vid = inputs[b * SEQ + t];
  float4 v = *reinterpret_cast<const float4*>(E + (size_t)vid * EMBD + e4);
  short4 o;
  o.x = f2bf(v.x); o.y = f2bf(v.y); o.z = f2bf(v.z); o.w = f2bf(v.w);
  *reinterpret_cast<short4*>(emb + (size_t)(t * BATCH + b) * EMBD + e4) = o;
}

// Gate epilogue for 2 statically-indexed accumulator rows (rule #20: R0 is a
// template constant so all ext_vector indexing is compile-time).
template<int R0>
__device__ __forceinline__ void gate_epi(const f32x4 (&za)[4], const f32x4 (&zb)[4],
                                         float (&c)[2], short (&hv)[2]) {
#pragma unroll
  for (int rr = 0; rr < 2; ++rr) {
    float zi = za[0][R0 + rr] + zb[0][R0 + rr];
    float zf = za[1][R0 + rr] + zb[1][R0 + rr];
    float zg = za[2][R0 + rr] + zb[2][R0 + rr];
    float zo = za[3][R0 + rr] + zb[3][R0 + rr];
    float ei  = __expf(-zi);
    float e2g = __expf(-2.f * zg);
    float ef  = __expf(-zf);
    float fg  = rcpf(1.f + ef);
    float it  = (1.f - e2g) * rcpf((1.f + ei) * (1.f + e2g));  // sig(i)*tanh(g)
    float cn  = fg * c[rr] + it;
    c[rr] = cn;
    float eo  = __expf(-zo);
    float e2c = __expf(-2.f * cn);
    hv[rr] = f2bf((1.f - e2c) * rcpf((1.f + eo) * (1.f + e2c)));  // sig(o)*tanh(c)
  }
}

// ---------------- K2: bidirectional LSTM + fused logits ----------------
// 64 blocks x 1024 threads (16 waves = 4/SIMD). Waves w and w+8 duplicate the
// same MFMAs (matrix pipe is ~7% busy -> duplication is free) and split the
// gate epilogue: half 0 takes acc rows 0-1, half 1 rows 2-3. Doubles wave TLP
// per SIMD and halves the serial VALU/trans work per wave.
__global__ void __launch_bounds__(1024, 1)
k_lstm(const short* __restrict__ emb,
       const float* __restrict__ Wx_f, const float* __restrict__ Wh_f, const float* __restrict__ b_f,
       const float* __restrict__ Wx_b, const float* __restrict__ Wh_b, const float* __restrict__ b_b,
       const float* __restrict__ Wd,
       float* __restrict__ logits_f, float* __restrict__ logits_b) {
  const int blk  = blockIdx.x;
  const int dir  = blk & 1;
  const int b0   = (blk >> 1) * 16;
  const int tid  = threadIdx.x;
  const int w    = tid >> 6;       // 0..15
  const int weff = w & 7;          // hid-col group
  const int half = w >> 3;         // 0: acc rows 0-1, 1: rows 2-3
  const int lane = tid & 63;
  const int quad = lane >> 4;      // 0..3
  const int mrow = lane & 15;      // A-frag row / C-frag col
  const int m0   = quad * 4;       // C-frag rows m0..m0+3
  const int hcol = weff * 16 + mrow;

  const float* WX = dir ? Wx_b : Wx_f;
  const float* WH = dir ? Wh_b : Wh_f;
  const float* BV = dir ? b_b  : b_f;
  float* LOG = dir ? logits_b : logits_f;

  // ---- load weights into register B-fragments (one-time) ----
  bf16x8 wxf[4][2], whf[4][4];
  float bias[4];
#pragma unroll
  for (int q = 0; q < 4; ++q) {
    int col = q * HID + hcol;
    bias[q] = BV[col];
#pragma unroll
    for (int kt = 0; kt < 2; ++kt) {
      bf16x8 f;
#pragma unroll
      for (int j = 0; j < 8; ++j) {
        int k = kt * 32 + quad * 8 + j;
        f[j] = f2bf(WX[k * GATES + col]);
      }
      wxf[q][kt] = f;
    }
#pragma unroll
    for (int kt = 0; kt < 4; ++kt) {
      bf16x8 f;
#pragma unroll
      for (int j = 0; j < 8; ++j) {
        int k = kt * 32 + quad * 8 + j;
        f[j] = f2bf(WH[k * GATES + col]);
      }
      whf[q][kt] = f;
    }
  }

  // ---- Wd staged in LDS (saves 16 VGPR vs register fragments) ----
  __shared__ __align__(16) short wd_lds[32][136];  // [col][k] bf16, padded
  {
    int idx = tid * 4;            // 1024 threads x 4 = 4096 = 32*128
    int col = idx >> 7, k0 = idx & 127;
#pragma unroll
    for (int j = 0; j < 4; ++j) {
      float v = (col < NST) ? Wd[(dir * HID + k0 + j) * NST + col] : 0.f;
      wd_lds[col][k0 + j] = f2bf(v);
    }
  }

  // ---- LDS: double-buffered swizzled h tile [16 rows][128 cols] bf16 ----
  __shared__ __align__(16) short hbuf[2][16 * 128];
  {
    int2* p = reinterpret_cast<int2*>(hbuf);
    int2 z; z.x = 0; z.y = 0;
    p[tid] = z;   // 1024 * 8B == 8192B
  }
  __syncthreads();

  const int  lcol = weff * 16 + mrow;          // logits col for waves 0-1
  const bool lw   = (w < 2);
  const bool lval = lw && (lcol < NST);

  float c[2] = {0.f, 0.f};

  const int t0 = dir ? (SEQ - 1) : 0;
  const short* efp0 = emb + ((size_t)(t0 * BATCH + b0 + mrow) * EMBD + quad * 8);
  bf16x8 xa0 = *reinterpret_cast<const bf16x8*>(efp0);
  bf16x8 xa1 = *reinterpret_cast<const bf16x8*>(efp0 + 32);

  for (int s = 0; s < SEQ; ++s) {
    const int p = s & 1;
    const int t = dir ? (SEQ - 1 - s) : s;
    // prefetch next x fragments
    const int sn = (s + 1 < SEQ) ? s + 1 : s;
    const int tn = dir ? (SEQ - 1 - sn) : sn;
    const short* efp = emb + ((size_t)(tn * BATCH + b0 + mrow) * EMBD + quad * 8);
    bf16x8 xb0 = *reinterpret_cast<const bf16x8*>(efp);
    bf16x8 xb1 = *reinterpret_cast<const bf16x8*>(efp + 32);

    // h_{s-1} A-fragments from previous buffer (swizzled ds_read_b128)
    bf16x8 hfr[4];
    const char* hb = reinterpret_cast<const char*>(hbuf[p ^ 1]);
#pragma unroll
    for (int kt = 0; kt < 4; ++kt) {
      unsigned off = (unsigned)((mrow * 128 + kt * 32 + quad * 8) * 2) ^ ((unsigned)(mrow & 7) << 4);
      hfr[kt] = *reinterpret_cast<const bf16x8*>(hb + off);
    }

    // z = bias + x@Wx + h@Wh ; two independent 3-deep chains per gate
    f32x4 za[4], zb[4];
#pragma unroll
    for (int q = 0; q < 4; ++q) {
      f32x4 a = {bias[q], bias[q], bias[q], bias[q]};
      a = __builtin_amdgcn_mfma_f32_16x16x32_bf16(xa0, wxf[q][0], a, 0, 0, 0);
      f32x4 b2 = {0.f, 0.f, 0.f, 0.f};
      b2 = __builtin_amdgcn_mfma_f32_16x16x32_bf16(xa1, wxf[q][1], b2, 0, 0, 0);
      a  = __builtin_amdgcn_mfma_f32_16x16x32_bf16(hfr[0], whf[q][0], a, 0, 0, 0);
      b2 = __builtin_amdgcn_mfma_f32_16x16x32_bf16(hfr[2], whf[q][2], b2, 0, 0, 0);
      a  = __builtin_amdgcn_mfma_f32_16x16x32_bf16(hfr[1], whf[q][1], a, 0, 0, 0);
      b2 = __builtin_amdgcn_mfma_f32_16x16x32_bf16(hfr[3], whf[q][3], b2, 0, 0, 0);
      za[q] = a; zb[q] = b2;
    }

    // fused logits for h_{s-1} (waves 0-1; Wd B-frags from LDS)
    if (lw && s > 0) {
      bf16x8 wdb[4];
#pragma unroll
      for (int kt = 0; kt < 4; ++kt)
        wdb[kt] = *reinterpret_cast<const bf16x8*>(&wd_lds[lcol][kt * 32 + quad * 8]);
      f32x4 la = {0.f, 0.f, 0.f, 0.f};
#pragma unroll
      for (int kt = 0; kt < 4; ++kt)
        la = __builtin_amdgcn_mfma_f32_16x16x32_bf16(hfr[kt], wdb[kt], la, 0, 0, 0);
      int tp = dir ? (t + 1) : (t - 1);
      if (lval) {
        float* dst = LOG + (size_t)tp * LROW + (size_t)(b0 + m0) * NST + lcol;
#pragma unroll
        for (int r = 0; r < 4; ++r) dst[r * NST] = la[r];
      }
    }

    // gate epilogue: half 0 -> rows m0..m0+1, half 1 -> rows m0+2..m0+3
    short hv[2];
    char* wb = reinterpret_cast<char*>(hbuf[p]);
    if (half == 0) {
      gate_epi<0>(za, zb, c, hv);
#pragma unroll
      for (int rr = 0; rr < 2; ++rr) {
        int m = m0 + rr;
        unsigned off = (unsigned)((m * 128 + hcol) * 2) ^ ((unsigned)(m & 7) << 4);
        *reinterpret_cast<short*>(wb + off) = hv[rr];
      }
    } else {
      gate_epi<2>(za, zb, c, hv);
#pragma unroll
      for (int rr = 0; rr < 2; ++rr) {
        int m = m0 + 2 + rr;
        unsigned off = (unsigned)((m * 128 + hcol) * 2) ^ ((unsigned)(m & 7) << 4);
        *reinterpret_cast<short*>(wb + off) = hv[rr];
      }
    }

    lds_barrier();   // lgkm-only; x loads + logit stores stay in flight
    xa0 = xb0; xa1 = xb1;
  }

  // final logits for h_{SEQ-1}
  if (lw) {
    const char* hb = reinterpret_cast<const char*>(hbuf[(SEQ - 1) & 1]);
    bf16x8 hfr[4];
#pragma unroll
    for (int kt = 0; kt < 4; ++kt) {
      unsigned off = (unsigned)((mrow * 128 + kt * 32 + quad * 8) * 2) ^ ((unsigned)(mrow & 7) << 4);
      hfr[kt] = *reinterpret_cast<const bf16x8*>(hb + off);
    }
    bf16x8 wdb[4];
#pragma unroll
    for (int kt = 0; kt < 4; ++kt)
      wdb[kt] = *reinterpret_cast<const bf16x8*>(&wd_lds[lcol][kt * 32 + quad * 8]);
    f32x4 la = {0.f, 0.f, 0.f, 0.f};
#pragma unroll
    for (int kt = 0; kt < 4; ++kt)
      la = __builtin_amdgcn_mfma_f32_16x16x32_bf16(hfr[kt], wdb[kt], la, 0, 0, 0);
    int tp = dir ? 0 : (SEQ - 1);
    if (lval) {
      float* dst = LOG + (size_t)tp * LROW + (size_t)(b0 + m0) * NST + lcol;
#pragma unroll
      for (int r = 0; r < 4; ++r) dst[r * NST] = la[r];
    }
  }
}

// ---------------- K3: CRF log-likelihood, one wave per batch row ----------------
// 8-deep raw-load prefetch ring: logits (75 MB) miss L2; serial chain must
// cover ~500-900 cyc load latency. pfa/pfb stay as raw loads (no combine)
// so the s_waitcnt lands 8 steps after issue.
__global__ void k_crf(const float* __restrict__ lf, const float* __restrict__ lb,
                      const float* __restrict__ bd, const float* __restrict__ Tm,
                      const int* __restrict__ labels, float* __restrict__ out) {
  const int wv   = threadIdx.x >> 6;
  const int lane = threadIdx.x & 63;
  const int b    = blockIdx.x * 2 + wv;
  __shared__ unsigned char lab[2][SEQ];

  // labels row -> LDS bytes; length = count(label != 0)
  int4 lv = *reinterpret_cast<const int4*>(labels + (size_t)b * SEQ + lane * 4);
  uchar4 lc;
  lc.x = (unsigned char)lv.x; lc.y = (unsigned char)lv.y;
  lc.z = (unsigned char)lv.z; lc.w = (unsigned char)lv.w;
  *reinterpret_cast<uchar4*>(&lab[wv][lane * 4]) = lc;
  int cnt = (lv.x != 0) + (lv.y != 0) + (lv.z != 0) + (lv.w != 0);
#pragma unroll
  for (int d = 32; d; d >>= 1) cnt += __shfl_xor(cnt, d);
  const int len = cnt;

  // unary + binary
  float ub = 0.f;
#pragma unroll
  for (int ii = 0; ii < 4; ++ii) {
    int p = ii * 64 + lane;
    int lp = lab[wv][p];
    if (p < len) {
      size_t o = (size_t)p * LROW + (size_t)b * NST + lp;
      ub += lf[o] + lb[o] + bd[lp];
    }
    if (p < SEQ - 1 && (p + 1) < len)
      ub += Tm[lp * NST + lab[wv][p + 1]];
  }
#pragma unroll
  for (int d = 32; d; d >>= 1) ub += __shfl_xor(ub, d);

  // forward algorithm. h9 = lane>>5 (9-state half), j = lane&31 (state).
  const int h9 = lane >> 5;
  const int j  = lane & 31;
  const int jj = (j < NST) ? j : 0;
  float Tcol[9];
#pragma unroll
  for (int i2 = 0; i2 < 9; ++i2) Tcol[i2] = Tm[(9 * h9 + i2) * NST + jj];
  const float bdj = bd[jj];
  const size_t rowoff = (size_t)b * NST + jj;

  float alpha = lf[rowoff] + lb[rowoff] + bdj;  // t = 0

  // prefetch ring: pfa/pfb[u] hold raw lf/lb for step t (consumed 8 later)
  float pfa[8], pfb[8];
#pragma unroll
  for (int u = 0; u < 8; ++u) {
    size_t o = (size_t)(1 + u) * LROW + rowoff;
    pfa[u] = lf[o]; pfb[u] = lb[o];
  }

  for (int tb = 1; tb < len; tb += 8) {
#pragma unroll
    for (int u = 0; u < 8; ++u) {
      int t = tb + u;
      if (t < len) {
        float lg = pfa[u] + pfb[u] + bdj;
        float tt[9];
#pragma unroll
        for (int i2 = 0; i2 < 9; ++i2)
          tt[i2] = __shfl(alpha, 9 * h9 + i2) + Tcol[i2];
        float ma = fmaxf(fmaxf(tt[0], tt[1]), fmaxf(tt[2], tt[3]));
        float mb = fmaxf(fmaxf(tt[4], tt[5]), fmaxf(tt[6], tt[7]));
        float m9 = fmaxf(fmaxf(ma, mb), tt[8]);
        float s0 = __expf(tt[0] - m9) + __expf(tt[1] - m9);
        float s1 = __expf(tt[2] - m9) + __expf(tt[3] - m9);
        float s2 = __expf(tt[4] - m9) + __expf(tt[5] - m9);
        float s3 = __expf(tt[6] - m9) + __expf(tt[7] - m9);
        float s9 = ((s0 + s1) + (s2 + s3)) + __expf(tt[8] - m9);
        float mo = __shfl_xor(m9, 32);
        float so = __shfl_xor(s9, 32);
        float m  = fmaxf(m9, mo);
        float s  = s9 * __expf(m9 - m) + so * __expf(mo - m);
        alpha = m + __logf(s) + lg;
      }
      int tn = t + 8; if (tn > SEQ - 1) tn = SEQ - 1;   // always in-bounds
      size_t o = (size_t)tn * LROW + rowoff;
      pfa[u] = lf[o]; pfb[u] = lb[o];
    }
  }

  // log_norm = LSE over states; reduce across lanes (lanes 0..17 valid)
  float v = (lane < NST) ? alpha : -1e30f;
  float mm = v;
#pragma unroll
  for (int d = 32; d; d >>= 1) mm = fmaxf(mm, __shfl_xor(mm, d));
  float e = (lane < NST) ? __expf(alpha - mm) : 0.f;
#pragma unroll
  for (int d = 32; d; d >>= 1) e += __shfl_xor(e, d);
  if (lane == 0) out[b] = ub - (mm + __logf(e));
}

// ---------------- K4: T passthrough (second tuple output) ----------------
__global__ void k_tcopy(const float* __restrict__ Tm, float* __restrict__ out) {
  int i = blockIdx.x * 256 + threadIdx.x;
  if (i < NST * NST) out[BATCH + i] = Tm[i];
}

extern "C" void kernel_launch(void* const* d_in, const int* in_sizes, int n_in,
                              void* d_out, int out_size, void* d_ws, size_t ws_size,
                              hipStream_t stream) {
  const int*   inputs = (const int*)d_in[0];
  const int*   labels = (const int*)d_in[1];
  const float* E      = (const float*)d_in[2];
  const float* Wx_f   = (const float*)d_in[3];
  const float* Wh_f   = (const float*)d_in[4];
  const float* b_f    = (const float*)d_in[5];
  const float* Wx_b   = (const float*)d_in[6];
  const float* Wh_b   = (const float*)d_in[7];
  const float* b_b    = (const float*)d_in[8];
  const float* Wd     = (const float*)d_in[9];
  const float* bd     = (const float*)d_in[10];
  const float* Tm     = (const float*)d_in[11];
  float* out = (float*)d_out;

  char* ws = (char*)d_ws;
  short* emb      = (short*)ws;                                  // 16,777,216 B
  float* logits_f = (float*)(ws + (size_t)16777216);             //  9,437,184 B
  float* logits_b = (float*)(ws + (size_t)16777216 + 9437184);   //  9,437,184 B

  k_embed<<<8192, 256, 0, stream>>>(inputs, E, emb);
  k_lstm<<<64, 1024, 0, stream>>>(emb, Wx_f, Wh_f, b_f, Wx_b, Wh_b, b_b, Wd,
                                  logits_f, logits_b);
  k_crf<<<256, 128, 0, stream>>>(logits_f, logits_b, bd, Tm, labels, out);
  k_tcopy<<<2, 256, 0, stream>>>(Tm, out);
}

// Round 6
// 432.519 us; speedup vs baseline: 5.0574x; 5.0574x over previous
//
#include <hip/hip_runtime.h>
#include <stdint.h>

#define BATCH 512
#define SEQ   256
#define EMBD  64
#define HID   128
#define GATES 512
#define NST   18
#define LROW  (BATCH * NST)   /* 9216 floats per time slice */

typedef short  bf16x8 __attribute__((ext_vector_type(8)));
typedef float  f32x4  __attribute__((ext_vector_type(4)));

__device__ __forceinline__ short f2bf(float f) {
  unsigned u = __float_as_uint(f);
  u = (u + 0x7FFFu + ((u >> 16) & 1u)) >> 16;
  return (short)u;
}
__device__ __forceinline__ float rcpf(float x) { return __builtin_amdgcn_rcpf(x); }

// lgkm-only barrier (vmem ops stay in flight across it).
__device__ __forceinline__ void lds_barrier() {
  __builtin_amdgcn_sched_barrier(0);
  asm volatile("s_waitcnt lgkmcnt(0)");
  __builtin_amdgcn_s_barrier();
  __builtin_amdgcn_sched_barrier(0);
}

// ---------------- K1: embedding gather, time-major bf16 ----------------
__global__ void k_embed(const int* __restrict__ inputs, const float* __restrict__ E,
                        short* __restrict__ emb) {
  int tid = blockIdx.x * 256 + threadIdx.x;   // 2^21 threads total
  int e4 = (tid & 15) << 2;
  int b  = (tid >> 4) & (BATCH - 1);
  int t  = tid >> 13;
  int vid = inputs[b * SEQ + t];
  float4 v = *reinterpret_cast<const float4*>(E + (size_t)vid * EMBD + e4);
  short4 o;
  o.x = f2bf(v.x); o.y = f2bf(v.y); o.z = f2bf(v.z); o.w = f2bf(v.w);
  *reinterpret_cast<short4*>(emb + (size_t)(t * BATCH + b) * EMBD + e4) = o;
}

// ---------------- K2: bidirectional LSTM + fused logits ----------------
// 64 blocks (1/CU): even=forward, odd=backward; block owns 16 batch rows.
// 8 waves; wave w owns hidden cols [16w,16w+16) across all 4 gates.
// __launch_bounds__(512) with NO min-waves arg: grid is 64 blocks -> always
// 1 block/CU = 2 waves/SIMD, where the VGPR budget is 256. The old (512,2)
// capped at 128 VGPR vs ~176 live -> compiler serialized the whole step
// (R4's 2600 cyc/step). R5's (1024,1) allocated 64 -> spilled weights.
__global__ void __launch_bounds__(512)
k_lstm(const short* __restrict__ emb,
       const float* __restrict__ Wx_f, const float* __restrict__ Wh_f, const float* __restrict__ b_f,
       const float* __restrict__ Wx_b, const float* __restrict__ Wh_b, const float* __restrict__ b_b,
       const float* __restrict__ Wd,
       float* __restrict__ logits_f, float* __restrict__ logits_b) {
  const int blk  = blockIdx.x;
  const int dir  = blk & 1;
  const int b0   = (blk >> 1) * 16;
  const int tid  = threadIdx.x;
  const int w    = tid >> 6;
  const int lane = tid & 63;
  const int quad = lane >> 4;      // 0..3
  const int mrow = lane & 15;      // A-frag row / C-frag col
  const int m0   = quad * 4;       // C-frag rows m0..m0+3
  const int hcol = w * 16 + mrow;  // hidden col this lane owns (0..127)

  const float* WX = dir ? Wx_b : Wx_f;
  const float* WH = dir ? Wh_b : Wh_f;
  const float* BV = dir ? b_b  : b_f;
  float* LOG = dir ? logits_b : logits_f;

  // ---- load weights into register B-fragments (one-time) ----
  bf16x8 wxf[4][2], whf[4][4], wdf[4];
  float bias[4];
#pragma unroll
  for (int q = 0; q < 4; ++q) {
    int col = q * HID + hcol;
    bias[q] = BV[col];
#pragma unroll
    for (int kt = 0; kt < 2; ++kt) {
      bf16x8 f;
#pragma unroll
      for (int j = 0; j < 8; ++j) {
        int k = kt * 32 + quad * 8 + j;
        f[j] = f2bf(WX[k * GATES + col]);
      }
      wxf[q][kt] = f;
    }
#pragma unroll
    for (int kt = 0; kt < 4; ++kt) {
      bf16x8 f;
#pragma unroll
      for (int j = 0; j < 8; ++j) {
        int k = kt * 32 + quad * 8 + j;
        f[j] = f2bf(WH[k * GATES + col]);
      }
      whf[q][kt] = f;
    }
  }
  const int  lcol = w * 16 + mrow;
  const bool lval = (w < 2) && (lcol < NST);
#pragma unroll
  for (int kt = 0; kt < 4; ++kt) {
    bf16x8 f;
#pragma unroll
    for (int j = 0; j < 8; ++j) {
      int k = kt * 32 + quad * 8 + j;
      f[j] = lval ? f2bf(Wd[(dir * HID + k) * NST + lcol]) : (short)0;
    }
    wdf[kt] = f;
  }

  // ---- LDS: double-buffered swizzled h tile [16 rows][128 cols] bf16 ----
  __shared__ __align__(16) short hbuf[2][16 * 128];
  {
    int4* p = reinterpret_cast<int4*>(hbuf);
    int4 z; z.x = 0; z.y = 0; z.z = 0; z.w = 0;
    p[tid] = z;   // 512 * 16B == 8192B
  }
  __syncthreads();

  float c[4] = {0.f, 0.f, 0.f, 0.f};
  f32x4 la[8];
#pragma unroll
  for (int i = 0; i < 8; ++i) { la[i][0]=0.f; la[i][1]=0.f; la[i][2]=0.f; la[i][3]=0.f; }

  const int t0 = dir ? (SEQ - 1) : 0;
  const short* efp0 = emb + ((size_t)(t0 * BATCH + b0 + mrow) * EMBD + quad * 8);
  bf16x8 xa0 = *reinterpret_cast<const bf16x8*>(efp0);
  bf16x8 xa1 = *reinterpret_cast<const bf16x8*>(efp0 + 32);

  for (int so = 0; so < SEQ; so += 8) {
#pragma unroll
    for (int si = 0; si < 8; ++si) {
      const int s = so + si;
      const int p = s & 1;
      // prefetch next x fragments
      const int sn = (s + 1 < SEQ) ? s + 1 : s;
      const int tn = dir ? (SEQ - 1 - sn) : sn;
      const short* efp = emb + ((size_t)(tn * BATCH + b0 + mrow) * EMBD + quad * 8);
      bf16x8 xb0 = *reinterpret_cast<const bf16x8*>(efp);
      bf16x8 xb1 = *reinterpret_cast<const bf16x8*>(efp + 32);

      // h_{s-1} A-fragments from previous buffer (swizzled ds_read_b128)
      bf16x8 hfr[4];
      const char* hb = reinterpret_cast<const char*>(hbuf[p ^ 1]);
#pragma unroll
      for (int kt = 0; kt < 4; ++kt) {
        unsigned off = (unsigned)((mrow * 128 + kt * 32 + quad * 8) * 2) ^ ((unsigned)(mrow & 7) << 4);
        hfr[kt] = *reinterpret_cast<const bf16x8*>(hb + off);
      }

      // z = bias + x@Wx + h@Wh ; two independent 3-deep chains per gate
      f32x4 za[4], zb[4];
#pragma unroll
      for (int q = 0; q < 4; ++q) {
        f32x4 a = {bias[q], bias[q], bias[q], bias[q]};
        a = __builtin_amdgcn_mfma_f32_16x16x32_bf16(xa0, wxf[q][0], a, 0, 0, 0);
        f32x4 b2 = {0.f, 0.f, 0.f, 0.f};
        b2 = __builtin_amdgcn_mfma_f32_16x16x32_bf16(xa1, wxf[q][1], b2, 0, 0, 0);
        a  = __builtin_amdgcn_mfma_f32_16x16x32_bf16(hfr[0], whf[q][0], a, 0, 0, 0);
        b2 = __builtin_amdgcn_mfma_f32_16x16x32_bf16(hfr[2], whf[q][2], b2, 0, 0, 0);
        a  = __builtin_amdgcn_mfma_f32_16x16x32_bf16(hfr[1], whf[q][1], a, 0, 0, 0);
        b2 = __builtin_amdgcn_mfma_f32_16x16x32_bf16(hfr[3], whf[q][3], b2, 0, 0, 0);
        za[q] = a; zb[q] = b2;
      }

      // gates (Keras order i,f,g,o); fused sigma*tanh: 5 exp + 3 rcp per elem
      short hv[4];
#pragma unroll
      for (int r = 0; r < 4; ++r) {
        float zi = za[0][r] + zb[0][r];
        float zf = za[1][r] + zb[1][r];
        float zg = za[2][r] + zb[2][r];
        float zo = za[3][r] + zb[3][r];
        float ei  = __expf(-zi);
        float e2g = __expf(-2.f * zg);
        float ef  = __expf(-zf);
        float fg  = rcpf(1.f + ef);
        float it  = (1.f - e2g) * rcpf((1.f + ei) * (1.f + e2g));  // sig(i)*tanh(g)
        float cn  = fg * c[r] + it;
        c[r] = cn;
        float eo  = __expf(-zo);
        float e2c = __expf(-2.f * cn);
        hv[r] = f2bf((1.f - e2c) * rcpf((1.f + eo) * (1.f + e2c)));  // sig(o)*tanh(c)
      }

      // write h_s (swizzled b16 stores)
      char* wb = reinterpret_cast<char*>(hbuf[p]);
#pragma unroll
      for (int r = 0; r < 4; ++r) {
        int m = m0 + r;
        unsigned off = (unsigned)((m * 128 + hcol) * 2) ^ ((unsigned)(m & 7) << 4);
        *reinterpret_cast<short*>(wb + off) = hv[r];
      }

      // fused logits for h_{s-1} -> REGISTER slot (no global store here)
      if (w < 2 && (so + si) > 0) {
        f32x4 l = {0.f, 0.f, 0.f, 0.f};
#pragma unroll
        for (int kt = 0; kt < 4; ++kt)
          l = __builtin_amdgcn_mfma_f32_16x16x32_bf16(hfr[kt], wdf[kt], l, 0, 0, 0);
        la[si] = l;
      }

      lds_barrier();   // lgkm-only; x loads stay in flight
      xa0 = xb0; xa1 = xb1;
    }

    // flush 8 logit slots (positions so+si-1); once per 8 steps the vmcnt
    // path eats the store-acks, instead of every step
    if (lval) {
#pragma unroll
      for (int si = 0; si < 8; ++si) {
        if (so == 0 && si == 0) continue;
        int pos = dir ? (SEQ - so - si) : (so + si - 1);
        float* dst = LOG + (size_t)pos * LROW + (size_t)(b0 + m0) * NST + lcol;
        dst[0]       = la[si][0];
        dst[NST]     = la[si][1];
        dst[2 * NST] = la[si][2];
        dst[3 * NST] = la[si][3];
      }
    }
  }

  // final logits for h_{SEQ-1}
  if (w < 2) {
    const char* hb = reinterpret_cast<const char*>(hbuf[(SEQ - 1) & 1]);
    bf16x8 hfr[4];
#pragma unroll
    for (int kt = 0; kt < 4; ++kt) {
      unsigned off = (unsigned)((mrow * 128 + kt * 32 + quad * 8) * 2) ^ ((unsigned)(mrow & 7) << 4);
      hfr[kt] = *reinterpret_cast<const bf16x8*>(hb + off);
    }
    f32x4 l = {0.f, 0.f, 0.f, 0.f};
#pragma unroll
    for (int kt = 0; kt < 4; ++kt)
      l = __builtin_amdgcn_mfma_f32_16x16x32_bf16(hfr[kt], wdf[kt], l, 0, 0, 0);
    int tp = dir ? 0 : (SEQ - 1);
    if (lval) {
      float* dst = LOG + (size_t)tp * LROW + (size_t)(b0 + m0) * NST + lcol;
#pragma unroll
      for (int r = 0; r < 4; ++r) dst[r * NST] = l[r];
    }
  }
}

// ---------------- K3: CRF log-likelihood, one wave per batch row ----------------
// 8-deep raw-load prefetch ring: logits (18.9 MB) mostly miss per-XCD L2;
// serial chain must cover ~300-900 cyc load latency. pfa/pfb stay raw
// (uncombined) so the s_waitcnt lands 8 steps after issue.
__global__ void k_crf(const float* __restrict__ lf, const float* __restrict__ lb,
                      const float* __restrict__ bd, const float* __restrict__ Tm,
                      const int* __restrict__ labels, float* __restrict__ out) {
  const int wv   = threadIdx.x >> 6;
  const int lane = threadIdx.x & 63;
  const int b    = blockIdx.x * 2 + wv;
  __shared__ unsigned char lab[2][SEQ];

  // labels row -> LDS bytes; length = count(label != 0)
  int4 lv = *reinterpret_cast<const int4*>(labels + (size_t)b * SEQ + lane * 4);
  uchar4 lc;
  lc.x = (unsigned char)lv.x; lc.y = (unsigned char)lv.y;
  lc.z = (unsigned char)lv.z; lc.w = (unsigned char)lv.w;
  *reinterpret_cast<uchar4*>(&lab[wv][lane * 4]) = lc;
  int cnt = (lv.x != 0) + (lv.y != 0) + (lv.z != 0) + (lv.w != 0);
#pragma unroll
  for (int d = 32; d; d >>= 1) cnt += __shfl_xor(cnt, d);
  const int len = cnt;

  // unary + binary
  float ub = 0.f;
#pragma unroll
  for (int ii = 0; ii < 4; ++ii) {
    int p = ii * 64 + lane;
    int lp = lab[wv][p];
    if (p < len) {
      size_t o = (size_t)p * LROW + (size_t)b * NST + lp;
      ub += lf[o] + lb[o] + bd[lp];
    }
    if (p < SEQ - 1 && (p + 1) < len)
      ub += Tm[lp * NST + lab[wv][p + 1]];
  }
#pragma unroll
  for (int d = 32; d; d >>= 1) ub += __shfl_xor(ub, d);

  // forward algorithm. h9 = lane>>5 (9-state half), j = lane&31 (state).
  const int h9 = lane >> 5;
  const int j  = lane & 31;
  const int jj = (j < NST) ? j : 0;
  float Tcol[9];
#pragma unroll
  for (int i2 = 0; i2 < 9; ++i2) Tcol[i2] = Tm[(9 * h9 + i2) * NST + jj];
  const float bdj = bd[jj];
  const size_t rowoff = (size_t)b * NST + jj;

  float alpha = lf[rowoff] + lb[rowoff] + bdj;  // t = 0

  // prefetch ring: pfa/pfb[u] hold raw lf/lb for step t (consumed 8 later)
  float pfa[8], pfb[8];
#pragma unroll
  for (int u = 0; u < 8; ++u) {
    size_t o = (size_t)(1 + u) * LROW + rowoff;
    pfa[u] = lf[o]; pfb[u] = lb[o];
  }

  for (int tb = 1; tb < len; tb += 8) {
#pragma unroll
    for (int u = 0; u < 8; ++u) {
      int t = tb + u;
      if (t < len) {
        float lg = pfa[u] + pfb[u] + bdj;
        float tt[9];
#pragma unroll
        for (int i2 = 0; i2 < 9; ++i2)
          tt[i2] = __shfl(alpha, 9 * h9 + i2) + Tcol[i2];
        float ma = fmaxf(fmaxf(tt[0], tt[1]), fmaxf(tt[2], tt[3]));
        float mb = fmaxf(fmaxf(tt[4], tt[5]), fmaxf(tt[6], tt[7]));
        float m9 = fmaxf(fmaxf(ma, mb), tt[8]);
        float s0 = __expf(tt[0] - m9) + __expf(tt[1] - m9);
        float s1 = __expf(tt[2] - m9) + __expf(tt[3] - m9);
        float s2 = __expf(tt[4] - m9) + __expf(tt[5] - m9);
        float s3 = __expf(tt[6] - m9) + __expf(tt[7] - m9);
        float s9 = ((s0 + s1) + (s2 + s3)) + __expf(tt[8] - m9);
        float mo = __shfl_xor(m9, 32);
        float so = __shfl_xor(s9, 32);
        float m  = fmaxf(m9, mo);
        float s  = s9 * __expf(m9 - m) + so * __expf(mo - m);
        alpha = m + __logf(s) + lg;
      }
      int tn = t + 8; if (tn > SEQ - 1) tn = SEQ - 1;   // always in-bounds
      size_t o = (size_t)tn * LROW + rowoff;
      pfa[u] = lf[o]; pfb[u] = lb[o];
    }
  }

  // log_norm = LSE over states; reduce across lanes (lanes 0..17 valid)
  float v = (lane < NST) ? alpha : -1e30f;
  float mm = v;
#pragma unroll
  for (int d = 32; d; d >>= 1) mm = fmaxf(mm, __shfl_xor(mm, d));
  float e = (lane < NST) ? __expf(alpha - mm) : 0.f;
#pragma unroll
  for (int d = 32; d; d >>= 1) e += __shfl_xor(e, d);
  if (lane == 0) out[b] = ub - (mm + __logf(e));
}

// ---------------- K4: T passthrough (second tuple output) ----------------
__global__ void k_tcopy(const float* __restrict__ Tm, float* __restrict__ out) {
  int i = blockIdx.x * 256 + threadIdx.x;
  if (i < NST * NST) out[BATCH + i] = Tm[i];
}

extern "C" void kernel_launch(void* const* d_in, const int* in_sizes, int n_in,
                              void* d_out, int out_size, void* d_ws, size_t ws_size,
                              hipStream_t stream) {
  const int*   inputs = (const int*)d_in[0];
  const int*   labels = (const int*)d_in[1];
  const float* E      = (const float*)d_in[2];
  const float* Wx_f   = (const float*)d_in[3];
  const float* Wh_f   = (const float*)d_in[4];
  const float* b_f    = (const float*)d_in[5];
  const float* Wx_b   = (const float*)d_in[6];
  const float* Wh_b   = (const float*)d_in[7];
  const float* b_b    = (const float*)d_in[8];
  const float* Wd     = (const float*)d_in[9];
  const float* bd     = (const float*)d_in[10];
  const float* Tm     = (const float*)d_in[11];
  float* out = (float*)d_out;

  char* ws = (char*)d_ws;
  short* emb      = (short*)ws;                                  // 16,777,216 B
  float* logits_f = (float*)(ws + (size_t)16777216);             //  9,437,184 B
  float* logits_b = (float*)(ws + (size_t)16777216 + 9437184);   //  9,437,184 B

  k_embed<<<8192, 256, 0, stream>>>(inputs, E, emb);
  k_lstm<<<64, 512, 0, stream>>>(emb, Wx_f, Wh_f, b_f, Wx_b, Wh_b, b_b, Wd,
                                 logits_f, logits_b);
  k_crf<<<256, 128, 0, stream>>>(logits_f, logits_b, bd, Tm, labels, out);
  k_tcopy<<<2, 256, 0, stream>>>(Tm, out);
}